// Round 2
// baseline (68325.061 us; speedup 1.0000x reference)
//
#include <hip/hip_runtime.h>

#define BB 64
#define TT 4096
#define IN0 32
#define HH 128
#define G3 384
#define NOUT 32

typedef _Float16 h2 __attribute__((ext_vector_type(2)));
typedef _Float16 h8 __attribute__((ext_vector_type(8)));
union H8 { h8 v; h2 p[4]; };

// One WG per batch element; wave-specialized single-barrier-per-step pipeline.
// Waves 0-7: layer-1 recurrence + next-step x-projection (gi0) + x staging.
// Waves 8-11: layer-0 recurrence + fused fc.
struct SM {
    alignas(16) _Float16 hf0[2][HH];   // h0 f16 (matvec operand), parity by step
    alignas(16) _Float16 hf1[2][HH];   // h1 f16
    alignas(16) float    hs1[2][HH];   // h1 f32 (fc reads full precision)
    alignas(16) float    gi0[2][G3];   // precomputed W_ih0·x[t]+b_ih0 for step t
    alignas(16) _Float16 xh[2][16][IN0]; // x staged f16, 16-step chunks
    alignas(16) float    pfc[2][NOUT * 9]; // fc partials (8-way K-split)
};

__device__ __forceinline__ float fast_sigmoid(float x) {
    x = fminf(fmaxf(x, -30.f), 30.f);
    float e = __expf(-x);
    return __builtin_amdgcn_rcpf(1.f + e);
}
__device__ __forceinline__ float fast_tanh(float x) {
    x = fminf(fmaxf(x, -15.f), 15.f);
    float e = __expf(-2.f * x);
    return (1.f - e) * __builtin_amdgcn_rcpf(1.f + e);
}
__device__ __forceinline__ float fdot2(h2 a, h2 b, float c) {
#if __has_builtin(__builtin_amdgcn_fdot2)
    return __builtin_amdgcn_fdot2(a, b, c, false);   // v_dot2_f32_f16, fp32 accum
#else
    return fmaf((float)a.x, (float)b.x, fmaf((float)a.y, (float)b.y, c));
#endif
}
__device__ __forceinline__ h2 cvt2(float a, float b) {
    h2 r; r.x = (_Float16)a; r.y = (_Float16)b; return r;
}
// quad-lane butterfly via DPP (in-register K-reduce, no LDS partials)
__device__ __forceinline__ float qxor1(float v) {   // lanes 0123 -> 1032
    return __int_as_float(__builtin_amdgcn_mov_dpp(__float_as_int(v), 0xB1, 0xF, 0xF, true));
}
__device__ __forceinline__ float qxor2(float v) {   // lanes 0123 -> 2301
    return __int_as_float(__builtin_amdgcn_mov_dpp(__float_as_int(v), 0x4E, 0xF, 0xF, true));
}

// ---------------- waves 0-7: layer 1 + gi0 precompute + x staging ----------------
__device__ __forceinline__ void role_L1(
    SM& sm, const float* __restrict__ xb,
    const float* __restrict__ W_ih1, const float* __restrict__ W_hh1,
    const float* __restrict__ b_ih1, const float* __restrict__ b_hh1,
    const float* __restrict__ W_ih0, const float* __restrict__ b_ih0,
    float* __restrict__ hstack_l1)
{
    const int tid = threadIdx.x;          // 0..511
    const int j = tid >> 2, kq = tid & 3; // 128 j x 4-way K split (quad lanes)

    h2 wi1[3][16], wh1[3][16], wi0[3][4];
    #pragma unroll
    for (int g = 0; g < 3; ++g) {
        const int row = j + g * HH;
        const float* pi = &W_ih1[row * HH + kq * 32];
        const float* ph = &W_hh1[row * HH + kq * 32];
        #pragma unroll
        for (int m = 0; m < 16; ++m) {
            float2 f;
            f = *(const float2*)&pi[2 * m]; wi1[g][m] = cvt2(f.x, f.y);
            f = *(const float2*)&ph[2 * m]; wh1[g][m] = cvt2(f.x, f.y);
        }
        const float* p0 = &W_ih0[row * IN0 + kq * 8];
        #pragma unroll
        for (int m = 0; m < 4; ++m) {
            float2 f = *(const float2*)&p0[2 * m]; wi0[g][m] = cvt2(f.x, f.y);
        }
    }
    const bool lead = (kq == 0);
    const float brz = lead ? b_ih1[j] + b_hh1[j] : 0.f;                 // r: gi+gh fused
    const float bzz = lead ? b_ih1[j + HH] + b_hh1[j + HH] : 0.f;       // z: gi+gh fused
    const float bin = lead ? b_ih1[j + 2 * HH] : 0.f;
    const float bhn = lead ? b_hh1[j + 2 * HH] : 0.f;
    const float bg0 = lead ? b_ih0[j] : 0.f;
    const float bg1 = lead ? b_ih0[j + HH] : 0.f;
    const float bg2 = lead ? b_ih0[j + 2 * HH] : 0.f;

    if (tid < HH) {                        // zero h state (both parities)
        sm.hf0[0][tid] = (_Float16)0.f; sm.hf0[1][tid] = (_Float16)0.f;
        sm.hf1[0][tid] = (_Float16)0.f; sm.hf1[1][tid] = (_Float16)0.f;
        sm.hs1[0][tid] = 0.f;            sm.hs1[1][tid] = 0.f;
    }
    if (tid < 128) {                       // stage x chunk 0 (steps 0..15)
        float4 f = ((const float4*)xb)[tid];
        ((h2*)&sm.xh[0][0][0])[2 * tid]     = cvt2(f.x, f.y);
        ((h2*)&sm.xh[0][0][0])[2 * tid + 1] = cvt2(f.z, f.w);
    }
    __syncthreads();                       // barrier #1
    {   // gi0 for step 0
        H8 xc; xc.v = *(const h8*)&sm.xh[0][0][kq * 8];
        float a0 = bg0, a1 = bg1, a2 = bg2;
        #pragma unroll
        for (int q = 0; q < 4; ++q) {
            a0 = fdot2(wi0[0][q], xc.p[q], a0);
            a1 = fdot2(wi0[1][q], xc.p[q], a1);
            a2 = fdot2(wi0[2][q], xc.p[q], a2);
        }
        a0 += qxor1(a0); a0 += qxor2(a0);
        a1 += qxor1(a1); a1 += qxor2(a1);
        a2 += qxor1(a2); a2 += qxor2(a2);
        if (lead) {
            sm.gi0[0][j] = a0; sm.gi0[0][j + HH] = a1; sm.gi0[0][j + 2 * HH] = a2;
        }
    }
    __syncthreads();                       // barrier #2

    float hprev = 0.f;
    float4 pf;
    for (int s = 0; s <= TT + 2; ++s) {
        const int cur = s & 1, nxt = cur ^ 1;
        if (tid < 128 && (s & 15) == 0 && s + 16 < TT)     // issue x chunk load
            pf = ((const float4*)(xb + (size_t)(s + 16) * IN0))[tid];
        if (s >= 1 && s <= TT) {                           // h1[s-1]
            float ar = brz, az = bzz, ain = bin, ahn = bhn;
            #pragma unroll
            for (int i = 0; i < 4; ++i) {
                const int sg = (i + kq) & 3;               // rotate: kill bank aliasing
                H8 h0c; h0c.v = *(const h8*)&sm.hf0[cur][kq * 32 + sg * 8];
                H8 h1c; h1c.v = *(const h8*)&sm.hf1[cur][kq * 32 + sg * 8];
                #pragma unroll
                for (int q = 0; q < 4; ++q) {
                    const int m = sg * 4 + q;
                    ar  = fdot2(wi1[0][m], h0c.p[q], ar);
                    ar  = fdot2(wh1[0][m], h1c.p[q], ar);
                    az  = fdot2(wi1[1][m], h0c.p[q], az);
                    az  = fdot2(wh1[1][m], h1c.p[q], az);
                    ain = fdot2(wi1[2][m], h0c.p[q], ain);
                    ahn = fdot2(wh1[2][m], h1c.p[q], ahn);
                }
            }
            ar  += qxor1(ar);  ar  += qxor2(ar);
            az  += qxor1(az);  az  += qxor2(az);
            ain += qxor1(ain); ain += qxor2(ain);
            ahn += qxor1(ahn); ahn += qxor2(ahn);
            float rg = fast_sigmoid(ar);
            float zg = fast_sigmoid(az);
            float ng = fast_tanh(ain + rg * ahn);
            float hn = (1.f - zg) * ng + zg * hprev;
            hprev = hn;
            if (kq == 0)      sm.hf1[nxt][j] = (_Float16)hn;
            else if (kq == 1) sm.hs1[nxt][j] = hn;
            if (s == TT && kq == 2) hstack_l1[j] = hn;
        }
        if (s <= TT - 2) {                                 // gi0 for step s+1
            const int t1 = s + 1;
            H8 xc; xc.v = *(const h8*)&sm.xh[(t1 >> 4) & 1][t1 & 15][kq * 8];
            float a0 = bg0, a1 = bg1, a2 = bg2;
            #pragma unroll
            for (int q = 0; q < 4; ++q) {
                a0 = fdot2(wi0[0][q], xc.p[q], a0);
                a1 = fdot2(wi0[1][q], xc.p[q], a1);
                a2 = fdot2(wi0[2][q], xc.p[q], a2);
            }
            a0 += qxor1(a0); a0 += qxor2(a0);
            a1 += qxor1(a1); a1 += qxor2(a1);
            a2 += qxor1(a2); a2 += qxor2(a2);
            if (lead) {
                sm.gi0[nxt][j] = a0;
                sm.gi0[nxt][j + HH] = a1;
                sm.gi0[nxt][j + 2 * HH] = a2;
            }
        }
        if (tid < 128 && (s & 15) == 8 && s + 8 < TT) {    // commit x chunk
            const int buf = ((s >> 4) + 1) & 1;
            ((h2*)&sm.xh[buf][0][0])[2 * tid]     = cvt2(pf.x, pf.y);
            ((h2*)&sm.xh[buf][0][0])[2 * tid + 1] = cvt2(pf.z, pf.w);
        }
        __syncthreads();                                   // the ONLY per-step barrier
    }
}

// ---------------- waves 8-11: layer 0 + fused fc ----------------
__device__ __forceinline__ void role_L0(
    SM& sm, const float* __restrict__ W_hh0, const float* __restrict__ b_hh0,
    const float* __restrict__ fc_w, const float* __restrict__ fc_b,
    float* __restrict__ outb, float* __restrict__ hstack_l0)
{
    const int u = threadIdx.x - 512;       // 0..255
    const int j = u >> 1, kq = u & 1;      // 128 j x 2-way K split (lane pairs)
    const int o = u & 31, ks = u >> 5;     // fc: 32 outputs x 8-way K split

    h2 wh0[3][32];
    #pragma unroll
    for (int g = 0; g < 3; ++g) {
        const float* ph = &W_hh0[(size_t)(j + g * HH) * HH + kq * 64];
        #pragma unroll
        for (int m = 0; m < 32; ++m) {
            float2 f = *(const float2*)&ph[2 * m];
            wh0[g][m] = cvt2(f.x, f.y);
        }
    }
    const bool lead = (kq == 0);
    const float bhr = lead ? b_hh0[j] : 0.f;
    const float bhz = lead ? b_hh0[j + HH] : 0.f;
    const float bhn = lead ? b_hh0[j + 2 * HH] : 0.f;
    float fcr[16];                          // register-resident fc row slice
    #pragma unroll
    for (int m = 0; m < 16; ++m) fcr[m] = fc_w[o * HH + ks * 16 + m];
    const float fcbr = (u < NOUT) ? fc_b[u] : 0.f;

    __syncthreads();                        // barrier #1 (match L1)
    __syncthreads();                        // barrier #2 (match L1)

    float hprev = 0.f;
    for (int s = 0; s <= TT + 2; ++s) {
        const int cur = s & 1, nxt = cur ^ 1;
        if (s <= TT - 1) {                  // h0[s]
            float ahr = bhr, ahz = bhz, ahn = bhn;
            #pragma unroll
            for (int i = 0; i < 8; ++i) {
                const int sg = (i + kq * 4) & 7;           // rotate: kill bank aliasing
                H8 hc; hc.v = *(const h8*)&sm.hf0[cur][kq * 64 + sg * 8];
                #pragma unroll
                for (int q = 0; q < 4; ++q) {
                    const int m = sg * 4 + q;
                    ahr = fdot2(wh0[0][m], hc.p[q], ahr);
                    ahz = fdot2(wh0[1][m], hc.p[q], ahz);
                    ahn = fdot2(wh0[2][m], hc.p[q], ahn);
                }
            }
            ahr += qxor1(ahr);
            ahz += qxor1(ahz);
            ahn += qxor1(ahn);
            const float gir = sm.gi0[cur][j];
            const float giz = sm.gi0[cur][j + HH];
            const float gin = sm.gi0[cur][j + 2 * HH];
            float rg = fast_sigmoid(gir + ahr);
            float zg = fast_sigmoid(giz + ahz);
            float ng = fast_tanh(gin + rg * ahn);
            float hn = (1.f - zg) * ng + zg * hprev;
            hprev = hn;
            if (kq == 0) sm.hf0[nxt][j] = (_Float16)hn;
            if (s == TT - 1 && kq == 1) hstack_l0[j] = hn;
        }
        if (s >= 2 && s <= TT + 1) {        // fc partial on h1[s-2]
            const float* hv = &sm.hs1[cur][ks * 16];
            float ssum = 0.f;
            #pragma unroll
            for (int m = 0; m < 16; ++m) ssum = fmaf(hv[m], fcr[m], ssum);
            sm.pfc[cur][o * 9 + ks] = ssum;
        }
        if (s >= 3 && u < NOUT) {           // fc reduce -> out[s-3]
            float ssum = fcbr;
            #pragma unroll
            for (int m = 0; m < 8; ++m) ssum += sm.pfc[nxt][u * 9 + m];
            outb[(size_t)(s - 3) * NOUT + u] = ssum;
        }
        __syncthreads();                    // the ONLY per-step barrier
    }
}

extern "C" __global__ void __launch_bounds__(768, 3)
gru_fused_kernel(
    const float* __restrict__ x,
    const float* __restrict__ W_ih0, const float* __restrict__ W_hh0,
    const float* __restrict__ b_ih0, const float* __restrict__ b_hh0,
    const float* __restrict__ W_ih1, const float* __restrict__ W_hh1,
    const float* __restrict__ b_ih1, const float* __restrict__ b_hh1,
    const float* __restrict__ fc_w, const float* __restrict__ fc_b,
    float* __restrict__ out, float* __restrict__ hstack)
{
    __shared__ SM sm;
    const int b = blockIdx.x;
    if (threadIdx.x < 512) {
        role_L1(sm, x + (size_t)b * TT * IN0,
                W_ih1, W_hh1, b_ih1, b_hh1, W_ih0, b_ih0,
                hstack + (size_t)(BB + b) * HH);
    } else {
        role_L0(sm, W_hh0, b_hh0, fc_w, fc_b,
                out + (size_t)b * TT * NOUT,
                hstack + (size_t)b * HH);
    }
}

extern "C" void kernel_launch(void* const* d_in, const int* in_sizes, int n_in,
                              void* d_out, int out_size, void* d_ws, size_t ws_size,
                              hipStream_t stream) {
    const float* x     = (const float*)d_in[0];
    const float* W_ih0 = (const float*)d_in[1];
    const float* W_hh0 = (const float*)d_in[2];
    const float* b_ih0 = (const float*)d_in[3];
    const float* b_hh0 = (const float*)d_in[4];
    const float* W_ih1 = (const float*)d_in[5];
    const float* W_hh1 = (const float*)d_in[6];
    const float* b_ih1 = (const float*)d_in[7];
    const float* b_hh1 = (const float*)d_in[8];
    const float* fc_w  = (const float*)d_in[9];
    const float* fc_b  = (const float*)d_in[10];

    float* out    = (float*)d_out;                 // [B,T,32]
    float* hstack = out + (size_t)BB * TT * NOUT;  // [2,B,128]

    gru_fused_kernel<<<BB, 768, 0, stream>>>(
        x, W_ih0, W_hh0, b_ih0, b_hh0,
        W_ih1, W_hh1, b_ih1, b_hh1,
        fc_w, fc_b, out, hstack);
}

// Round 3
// 5195.422 us; speedup vs baseline: 13.1510x; 13.1510x over previous
//
#include <hip/hip_runtime.h>

#define BB 64
#define TT 4096
#define IN0 32
#define HH 128
#define G3 384
#define NOUT 32

typedef _Float16 h2 __attribute__((ext_vector_type(2)));
typedef _Float16 h8 __attribute__((ext_vector_type(8)));
union H8 { h8 v; h2 p[4]; };

// One WG per batch element; wave-specialized single-barrier-per-step pipeline.
// Waves 0-7: layer-1 recurrence + next-step x-projection (gi0) + x staging.
// Waves 8-11: layer-0 recurrence + fused fc.
// ALL weight-array indices are compile-time constants (rule #20: runtime-indexed
// register arrays go to scratch -- round 2's 12x regression).
struct SM {
    alignas(16) _Float16 hf0[2][HH];   // h0 f16 (matvec operand), parity by step
    alignas(16) _Float16 hf1[2][HH];   // h1 f16
    alignas(16) float    hs1[2][HH];   // h1 f32 (fc reads full precision)
    alignas(16) float    gi0[2][G3];   // precomputed W_ih0·x[t]+b_ih0 for step t
    alignas(16) _Float16 xh[2][16][IN0]; // x staged f16, 16-step chunks
    alignas(16) float    pfc[2][NOUT * 9]; // fc partials (8-way K-split)
};

__device__ __forceinline__ float fast_sigmoid(float x) {
    x = fminf(fmaxf(x, -30.f), 30.f);
    float e = __expf(-x);
    return __builtin_amdgcn_rcpf(1.f + e);
}
__device__ __forceinline__ float fast_tanh(float x) {
    x = fminf(fmaxf(x, -15.f), 15.f);
    float e = __expf(-2.f * x);
    return (1.f - e) * __builtin_amdgcn_rcpf(1.f + e);
}
__device__ __forceinline__ float fdot2(h2 a, h2 b, float c) {
#if __has_builtin(__builtin_amdgcn_fdot2)
    return __builtin_amdgcn_fdot2(a, b, c, false);   // v_dot2_f32_f16, fp32 accum
#else
    return fmaf((float)a.x, (float)b.x, fmaf((float)a.y, (float)b.y, c));
#endif
}
__device__ __forceinline__ h2 cvt2(float a, float b) {
    h2 r; r.x = (_Float16)a; r.y = (_Float16)b; return r;
}
// quad-lane butterfly via DPP (in-register K-reduce, no LDS partials)
__device__ __forceinline__ float qxor1(float v) {   // lanes 0123 -> 1032
    return __int_as_float(__builtin_amdgcn_mov_dpp(__float_as_int(v), 0xB1, 0xF, 0xF, true));
}
__device__ __forceinline__ float qxor2(float v) {   // lanes 0123 -> 2301
    return __int_as_float(__builtin_amdgcn_mov_dpp(__float_as_int(v), 0x4E, 0xF, 0xF, true));
}

// ---------------- waves 0-7: layer 1 + gi0 precompute + x staging ----------------
__device__ __forceinline__ void role_L1(
    SM& sm, const float* __restrict__ xb,
    const float* __restrict__ W_ih1, const float* __restrict__ W_hh1,
    const float* __restrict__ b_ih1, const float* __restrict__ b_hh1,
    const float* __restrict__ W_ih0, const float* __restrict__ b_ih0,
    float* __restrict__ hstack_l1)
{
    const int tid = threadIdx.x;          // 0..511
    const int j = tid >> 2, kq = tid & 3; // 128 j x 4-way K split (quad lanes)

    h2 wi1[3][16], wh1[3][16], wi0[3][4];
    #pragma unroll
    for (int g = 0; g < 3; ++g) {
        const int row = j + g * HH;
        const float* pi = &W_ih1[row * HH + kq * 32];
        const float* ph = &W_hh1[row * HH + kq * 32];
        #pragma unroll
        for (int m = 0; m < 16; ++m) {
            float2 f;
            f = *(const float2*)&pi[2 * m]; wi1[g][m] = cvt2(f.x, f.y);
            f = *(const float2*)&ph[2 * m]; wh1[g][m] = cvt2(f.x, f.y);
        }
        const float* p0 = &W_ih0[row * IN0 + kq * 8];
        #pragma unroll
        for (int m = 0; m < 4; ++m) {
            float2 f = *(const float2*)&p0[2 * m]; wi0[g][m] = cvt2(f.x, f.y);
        }
    }
    const bool lead = (kq == 0);
    const float brz = lead ? b_ih1[j] + b_hh1[j] : 0.f;                 // r: gi+gh fused
    const float bzz = lead ? b_ih1[j + HH] + b_hh1[j + HH] : 0.f;       // z: gi+gh fused
    const float bin = lead ? b_ih1[j + 2 * HH] : 0.f;
    const float bhn = lead ? b_hh1[j + 2 * HH] : 0.f;
    const float bg0 = lead ? b_ih0[j] : 0.f;
    const float bg1 = lead ? b_ih0[j + HH] : 0.f;
    const float bg2 = lead ? b_ih0[j + 2 * HH] : 0.f;

    if (tid < HH) {                        // zero h state (both parities)
        sm.hf0[0][tid] = (_Float16)0.f; sm.hf0[1][tid] = (_Float16)0.f;
        sm.hf1[0][tid] = (_Float16)0.f; sm.hf1[1][tid] = (_Float16)0.f;
        sm.hs1[0][tid] = 0.f;            sm.hs1[1][tid] = 0.f;
    }
    if (tid < 128) {                       // stage x chunk 0 (steps 0..15)
        float4 f = ((const float4*)xb)[tid];
        ((h2*)&sm.xh[0][0][0])[2 * tid]     = cvt2(f.x, f.y);
        ((h2*)&sm.xh[0][0][0])[2 * tid + 1] = cvt2(f.z, f.w);
    }
    __syncthreads();                       // barrier #1
    {   // gi0 for step 0
        H8 xc; xc.v = *(const h8*)&sm.xh[0][0][kq * 8];
        float a0 = bg0, a1 = bg1, a2 = bg2;
        #pragma unroll
        for (int q = 0; q < 4; ++q) {
            a0 = fdot2(wi0[0][q], xc.p[q], a0);
            a1 = fdot2(wi0[1][q], xc.p[q], a1);
            a2 = fdot2(wi0[2][q], xc.p[q], a2);
        }
        a0 += qxor1(a0); a0 += qxor2(a0);
        a1 += qxor1(a1); a1 += qxor2(a1);
        a2 += qxor1(a2); a2 += qxor2(a2);
        if (lead) {
            sm.gi0[0][j] = a0; sm.gi0[0][j + HH] = a1; sm.gi0[0][j + 2 * HH] = a2;
        }
    }
    __syncthreads();                       // barrier #2

    float hprev = 0.f;
    float4 pf;
    for (int s = 0; s <= TT + 2; ++s) {
        const int cur = s & 1, nxt = cur ^ 1;
        if (tid < 128 && (s & 15) == 0 && s + 16 < TT)     // issue x chunk load
            pf = ((const float4*)(xb + (size_t)(s + 16) * IN0))[tid];
        if (s >= 1 && s <= TT) {                           // h1[s-1]
            float ar = brz, az = bzz, ain = bin, ahn = bhn;
            #pragma unroll
            for (int i = 0; i < 4; ++i) {                  // STATIC index: i, q only
                H8 h0c; h0c.v = *(const h8*)&sm.hf0[cur][kq * 32 + i * 8];
                H8 h1c; h1c.v = *(const h8*)&sm.hf1[cur][kq * 32 + i * 8];
                #pragma unroll
                for (int q = 0; q < 4; ++q) {
                    const int m = 4 * i + q;
                    ar  = fdot2(wi1[0][m], h0c.p[q], ar);
                    ar  = fdot2(wh1[0][m], h1c.p[q], ar);
                    az  = fdot2(wi1[1][m], h0c.p[q], az);
                    az  = fdot2(wh1[1][m], h1c.p[q], az);
                    ain = fdot2(wi1[2][m], h0c.p[q], ain);
                    ahn = fdot2(wh1[2][m], h1c.p[q], ahn);
                }
            }
            ar  += qxor1(ar);  ar  += qxor2(ar);
            az  += qxor1(az);  az  += qxor2(az);
            ain += qxor1(ain); ain += qxor2(ain);
            ahn += qxor1(ahn); ahn += qxor2(ahn);
            float rg = fast_sigmoid(ar);
            float zg = fast_sigmoid(az);
            float ng = fast_tanh(ain + rg * ahn);
            float hn = (1.f - zg) * ng + zg * hprev;
            hprev = hn;
            if (kq == 0)      sm.hf1[nxt][j] = (_Float16)hn;
            else if (kq == 1) sm.hs1[nxt][j] = hn;
            if (s == TT && kq == 2) hstack_l1[j] = hn;
        }
        if (s <= TT - 2) {                                 // gi0 for step s+1
            const int t1 = s + 1;
            H8 xc; xc.v = *(const h8*)&sm.xh[(t1 >> 4) & 1][t1 & 15][kq * 8];
            float a0 = bg0, a1 = bg1, a2 = bg2;
            #pragma unroll
            for (int q = 0; q < 4; ++q) {
                a0 = fdot2(wi0[0][q], xc.p[q], a0);
                a1 = fdot2(wi0[1][q], xc.p[q], a1);
                a2 = fdot2(wi0[2][q], xc.p[q], a2);
            }
            a0 += qxor1(a0); a0 += qxor2(a0);
            a1 += qxor1(a1); a1 += qxor2(a1);
            a2 += qxor1(a2); a2 += qxor2(a2);
            if (lead) {
                sm.gi0[nxt][j] = a0;
                sm.gi0[nxt][j + HH] = a1;
                sm.gi0[nxt][j + 2 * HH] = a2;
            }
        }
        if (tid < 128 && (s & 15) == 8 && s + 8 < TT) {    // commit x chunk
            const int buf = ((s >> 4) + 1) & 1;
            ((h2*)&sm.xh[buf][0][0])[2 * tid]     = cvt2(pf.x, pf.y);
            ((h2*)&sm.xh[buf][0][0])[2 * tid + 1] = cvt2(pf.z, pf.w);
        }
        __syncthreads();                                   // the ONLY per-step barrier
    }
}

// ---------------- waves 8-11: layer 0 + fused fc ----------------
__device__ __forceinline__ void role_L0(
    SM& sm, const float* __restrict__ W_hh0, const float* __restrict__ b_hh0,
    const float* __restrict__ fc_w, const float* __restrict__ fc_b,
    float* __restrict__ outb, float* __restrict__ hstack_l0)
{
    const int u = threadIdx.x - 512;       // 0..255
    const int j = u >> 1, kq = u & 1;      // 128 j x 2-way K split (lane pairs)
    const int o = u & 31, ks = u >> 5;     // fc: 32 outputs x 8-way K split

    h2 wh0[3][32];
    #pragma unroll
    for (int g = 0; g < 3; ++g) {
        const float* ph = &W_hh0[(size_t)(j + g * HH) * HH + kq * 64];
        #pragma unroll
        for (int m = 0; m < 32; ++m) {
            float2 f = *(const float2*)&ph[2 * m];
            wh0[g][m] = cvt2(f.x, f.y);
        }
    }
    const bool lead = (kq == 0);
    const float bhr = lead ? b_hh0[j] : 0.f;
    const float bhz = lead ? b_hh0[j + HH] : 0.f;
    const float bhn = lead ? b_hh0[j + 2 * HH] : 0.f;
    float fcr[16];                          // register-resident fc row slice
    #pragma unroll
    for (int m = 0; m < 16; ++m) fcr[m] = fc_w[o * HH + ks * 16 + m];
    const float fcbr = (u < NOUT) ? fc_b[u] : 0.f;

    __syncthreads();                        // barrier #1 (match L1)
    __syncthreads();                        // barrier #2 (match L1)

    float hprev = 0.f;
    for (int s = 0; s <= TT + 2; ++s) {
        const int cur = s & 1, nxt = cur ^ 1;
        if (s <= TT - 1) {                  // h0[s]
            float ahr = bhr, ahz = bhz, ahn = bhn;
            #pragma unroll
            for (int i = 0; i < 8; ++i) {   // STATIC index: i, q only
                H8 hc; hc.v = *(const h8*)&sm.hf0[cur][kq * 64 + i * 8];
                #pragma unroll
                for (int q = 0; q < 4; ++q) {
                    const int m = 4 * i + q;
                    ahr = fdot2(wh0[0][m], hc.p[q], ahr);
                    ahz = fdot2(wh0[1][m], hc.p[q], ahz);
                    ahn = fdot2(wh0[2][m], hc.p[q], ahn);
                }
            }
            ahr += qxor1(ahr);
            ahz += qxor1(ahz);
            ahn += qxor1(ahn);
            const float gir = sm.gi0[cur][j];
            const float giz = sm.gi0[cur][j + HH];
            const float gin = sm.gi0[cur][j + 2 * HH];
            float rg = fast_sigmoid(gir + ahr);
            float zg = fast_sigmoid(giz + ahz);
            float ng = fast_tanh(gin + rg * ahn);
            float hn = (1.f - zg) * ng + zg * hprev;
            hprev = hn;
            if (kq == 0) sm.hf0[nxt][j] = (_Float16)hn;
            if (s == TT - 1 && kq == 1) hstack_l0[j] = hn;
        }
        if (s >= 2 && s <= TT + 1) {        // fc partial on h1[s-2]
            const float* hv = &sm.hs1[cur][ks * 16];
            float ssum = 0.f;
            #pragma unroll
            for (int m = 0; m < 16; ++m) ssum = fmaf(hv[m], fcr[m], ssum);
            sm.pfc[cur][o * 9 + ks] = ssum;
        }
        if (s >= 3 && u < NOUT) {           // fc reduce -> out[s-3]
            float ssum = fcbr;
            #pragma unroll
            for (int m = 0; m < 8; ++m) ssum += sm.pfc[nxt][u * 9 + m];
            outb[(size_t)(s - 3) * NOUT + u] = ssum;
        }
        __syncthreads();                    // the ONLY per-step barrier
    }
}

extern "C" __global__ void __launch_bounds__(768, 3)
gru_fused_kernel(
    const float* __restrict__ x,
    const float* __restrict__ W_ih0, const float* __restrict__ W_hh0,
    const float* __restrict__ b_ih0, const float* __restrict__ b_hh0,
    const float* __restrict__ W_ih1, const float* __restrict__ W_hh1,
    const float* __restrict__ b_ih1, const float* __restrict__ b_hh1,
    const float* __restrict__ fc_w, const float* __restrict__ fc_b,
    float* __restrict__ out, float* __restrict__ hstack)
{
    __shared__ SM sm;
    const int b = blockIdx.x;
    if (threadIdx.x < 512) {
        role_L1(sm, x + (size_t)b * TT * IN0,
                W_ih1, W_hh1, b_ih1, b_hh1, W_ih0, b_ih0,
                hstack + (size_t)(BB + b) * HH);
    } else {
        role_L0(sm, W_hh0, b_hh0, fc_w, fc_b,
                out + (size_t)b * TT * NOUT,
                hstack + (size_t)b * HH);
    }
}

extern "C" void kernel_launch(void* const* d_in, const int* in_sizes, int n_in,
                              void* d_out, int out_size, void* d_ws, size_t ws_size,
                              hipStream_t stream) {
    const float* x     = (const float*)d_in[0];
    const float* W_ih0 = (const float*)d_in[1];
    const float* W_hh0 = (const float*)d_in[2];
    const float* b_ih0 = (const float*)d_in[3];
    const float* b_hh0 = (const float*)d_in[4];
    const float* W_ih1 = (const float*)d_in[5];
    const float* W_hh1 = (const float*)d_in[6];
    const float* b_ih1 = (const float*)d_in[7];
    const float* b_hh1 = (const float*)d_in[8];
    const float* fc_w  = (const float*)d_in[9];
    const float* fc_b  = (const float*)d_in[10];

    float* out    = (float*)d_out;                 // [B,T,32]
    float* hstack = out + (size_t)BB * TT * NOUT;  // [2,B,128]

    gru_fused_kernel<<<BB, 768, 0, stream>>>(
        x, W_ih0, W_hh0, b_ih0, b_hh0,
        W_ih1, W_hh1, b_ih1, b_hh1,
        fc_w, fc_b, out, hstack);
}

// Round 4
// 5145.523 us; speedup vs baseline: 13.2785x; 1.0097x over previous
//
#include <hip/hip_runtime.h>

#define BB 64
#define TT 4096
#define IN0 32
#define HH 128
#define G3 384
#define NOUT 32

typedef _Float16 h2 __attribute__((ext_vector_type(2)));
typedef _Float16 h8 __attribute__((ext_vector_type(8)));
union H8 { h8 v; h2 p[4]; };

// One WG per batch element; wave-specialized single-barrier-per-step pipeline.
// Waves 0-7: layer-1 recurrence + next-step x-projection (gi0) + x staging + out flush.
// Waves 8-11: layer-0 recurrence + fused fc (reduce -> LDS ring, no per-step global store).
// ALL weight-array indices are compile-time constants (rule #20).
struct SM {
    alignas(16) _Float16 hf0[2][HH];   // h0 f16 (matvec operand), parity by step
    alignas(16) _Float16 hf1[2][HH];   // h1 f16
    alignas(16) float    hs1[2][HH];   // h1 f32 (fc reads full precision)
    alignas(16) float    gi0[2][G3];   // precomputed W_ih0·x[t]+b_ih0 for step t
    alignas(16) _Float16 xh[2][16][IN0]; // x staged f16, 16-step chunks
    alignas(16) float    pfc[2][NOUT * 9]; // fc partials (8-way K-split)
    alignas(16) float    outbuf[32][NOUT]; // out ring: 32 steps x 32 floats (flushed /16)
};

__device__ __forceinline__ float fast_sigmoid(float x) {
    x = fminf(fmaxf(x, -30.f), 30.f);
    float e = __expf(-x);
    return __builtin_amdgcn_rcpf(1.f + e);
}
__device__ __forceinline__ float fast_tanh(float x) {
    x = fminf(fmaxf(x, -15.f), 15.f);
    float e = __expf(-2.f * x);
    return (1.f - e) * __builtin_amdgcn_rcpf(1.f + e);
}
__device__ __forceinline__ float fdot2(h2 a, h2 b, float c) {
#if __has_builtin(__builtin_amdgcn_fdot2)
    return __builtin_amdgcn_fdot2(a, b, c, false);   // v_dot2_f32_f16, fp32 accum
#else
    return fmaf((float)a.x, (float)b.x, fmaf((float)a.y, (float)b.y, c));
#endif
}
__device__ __forceinline__ h2 cvt2(float a, float b) {
    h2 r; r.x = (_Float16)a; r.y = (_Float16)b; return r;
}
// quad-lane butterfly via DPP (in-register K-reduce, no LDS partials)
__device__ __forceinline__ float qxor1(float v) {   // lanes 0123 -> 1032
    return __int_as_float(__builtin_amdgcn_mov_dpp(__float_as_int(v), 0xB1, 0xF, 0xF, true));
}
__device__ __forceinline__ float qxor2(float v) {   // lanes 0123 -> 2301
    return __int_as_float(__builtin_amdgcn_mov_dpp(__float_as_int(v), 0x4E, 0xF, 0xF, true));
}

// ---------------- waves 0-7: layer 1 + gi0 precompute + x staging + out flush ----------------
__device__ __forceinline__ void role_L1(
    SM& sm, const float* __restrict__ xb,
    const float* __restrict__ W_ih1, const float* __restrict__ W_hh1,
    const float* __restrict__ b_ih1, const float* __restrict__ b_hh1,
    const float* __restrict__ W_ih0, const float* __restrict__ b_ih0,
    float* __restrict__ outb, float* __restrict__ hstack_l1)
{
    const int tid = threadIdx.x;          // 0..511
    const int j = tid >> 2, kq = tid & 3; // 128 j x 4-way K split (quad lanes)

    h2 wi1[3][16], wh1[3][16], wi0[3][4];
    #pragma unroll
    for (int g = 0; g < 3; ++g) {
        const int row = j + g * HH;
        const float* pi = &W_ih1[row * HH + kq * 32];
        const float* ph = &W_hh1[row * HH + kq * 32];
        #pragma unroll
        for (int m = 0; m < 16; ++m) {
            float2 f;
            f = *(const float2*)&pi[2 * m]; wi1[g][m] = cvt2(f.x, f.y);
            f = *(const float2*)&ph[2 * m]; wh1[g][m] = cvt2(f.x, f.y);
        }
        const float* p0 = &W_ih0[row * IN0 + kq * 8];
        #pragma unroll
        for (int m = 0; m < 4; ++m) {
            float2 f = *(const float2*)&p0[2 * m]; wi0[g][m] = cvt2(f.x, f.y);
        }
    }
    const bool lead = (kq == 0);
    const float brz = lead ? b_ih1[j] + b_hh1[j] : 0.f;                 // r: gi+gh biases
    const float bzz = lead ? b_ih1[j + HH] + b_hh1[j + HH] : 0.f;       // z: gi+gh biases
    const float bin = lead ? b_ih1[j + 2 * HH] : 0.f;
    const float bhn = lead ? b_hh1[j + 2 * HH] : 0.f;
    const float bg0 = lead ? b_ih0[j] : 0.f;
    const float bg1 = lead ? b_ih0[j + HH] : 0.f;
    const float bg2 = lead ? b_ih0[j + 2 * HH] : 0.f;

    if (tid < HH) {                        // zero h state (both parities)
        sm.hf0[0][tid] = (_Float16)0.f; sm.hf0[1][tid] = (_Float16)0.f;
        sm.hf1[0][tid] = (_Float16)0.f; sm.hf1[1][tid] = (_Float16)0.f;
        sm.hs1[0][tid] = 0.f;            sm.hs1[1][tid] = 0.f;
    }
    if (tid < 128) {                       // stage x chunk 0 (steps 0..15)
        float4 f = ((const float4*)xb)[tid];
        ((h2*)&sm.xh[0][0][0])[2 * tid]     = cvt2(f.x, f.y);
        ((h2*)&sm.xh[0][0][0])[2 * tid + 1] = cvt2(f.z, f.w);
    }
    __syncthreads();                       // barrier #1
    {   // gi0 for step 0
        H8 xc; xc.v = *(const h8*)&sm.xh[0][0][kq * 8];
        float a0 = bg0, a1 = bg1, a2 = bg2;
        #pragma unroll
        for (int q = 0; q < 4; ++q) {
            a0 = fdot2(wi0[0][q], xc.p[q], a0);
            a1 = fdot2(wi0[1][q], xc.p[q], a1);
            a2 = fdot2(wi0[2][q], xc.p[q], a2);
        }
        a0 += qxor1(a0); a0 += qxor2(a0);
        a1 += qxor1(a1); a1 += qxor2(a1);
        a2 += qxor1(a2); a2 += qxor2(a2);
        if (lead) {
            sm.gi0[0][j] = a0; sm.gi0[0][j + HH] = a1; sm.gi0[0][j + 2 * HH] = a2;
        }
    }
    __syncthreads();                       // barrier #2

    float hprev = 0.f;
    float4 pf;
    for (int s = 0; s <= TT + 4; ++s) {
        const int cur = s & 1, nxt = cur ^ 1;
        if (tid < 128 && (s & 15) == 0 && s + 16 < TT)     // issue x chunk load
            pf = ((const float4*)(xb + (size_t)(s + 16) * IN0))[tid];
        // out flush: 16 rows (2 KB) every 16 steps, coalesced, mid-body so the
        // store latency hides under the rest of the step (no per-step vmcnt drain)
        if (tid >= 256 && tid < 384 && (s & 15) == 4 && s >= 20 && (s >> 4) <= 256) {
            const int k = tid - 256;
            const int fb = ((s >> 4) - 1) * 16;            // first t of flushed block
            const int t = fb + (k >> 3);
            float4 v = *(const float4*)&sm.outbuf[t & 31][(k & 7) * 4];
            *(float4*)&outb[(size_t)t * NOUT + (k & 7) * 4] = v;
        }
        if (s >= 1 && s <= TT) {                           // h1[s-1]
            // split accumulators: 16-deep chains instead of 32-deep
            float ari = brz, arh = 0.f, azi = bzz, azh = 0.f, ain = bin, ahn = bhn;
            #pragma unroll
            for (int i = 0; i < 4; ++i) {                  // STATIC indices only
                H8 h0c; h0c.v = *(const h8*)&sm.hf0[cur][kq * 32 + i * 8];
                H8 h1c; h1c.v = *(const h8*)&sm.hf1[cur][kq * 32 + i * 8];
                #pragma unroll
                for (int q = 0; q < 4; ++q) {
                    const int m = 4 * i + q;
                    ari = fdot2(wi1[0][m], h0c.p[q], ari);
                    arh = fdot2(wh1[0][m], h1c.p[q], arh);
                    azi = fdot2(wi1[1][m], h0c.p[q], azi);
                    azh = fdot2(wh1[1][m], h1c.p[q], azh);
                    ain = fdot2(wi1[2][m], h0c.p[q], ain);
                    ahn = fdot2(wh1[2][m], h1c.p[q], ahn);
                }
            }
            float ar = ari + arh, az = azi + azh;
            ar  += qxor1(ar);  ar  += qxor2(ar);
            az  += qxor1(az);  az  += qxor2(az);
            ain += qxor1(ain); ain += qxor2(ain);
            ahn += qxor1(ahn); ahn += qxor2(ahn);
            float rg = fast_sigmoid(ar);
            float zg = fast_sigmoid(az);
            float ng = fast_tanh(ain + rg * ahn);
            float hn = (1.f - zg) * ng + zg * hprev;
            hprev = hn;
            if (kq == 0)      sm.hf1[nxt][j] = (_Float16)hn;
            else if (kq == 1) sm.hs1[nxt][j] = hn;
            if (s == TT && kq == 2) hstack_l1[j] = hn;
        }
        if (s <= TT - 2) {                                 // gi0 for step s+1
            const int t1 = s + 1;
            H8 xc; xc.v = *(const h8*)&sm.xh[(t1 >> 4) & 1][t1 & 15][kq * 8];
            float a0 = bg0, a1 = bg1, a2 = bg2;
            #pragma unroll
            for (int q = 0; q < 4; ++q) {
                a0 = fdot2(wi0[0][q], xc.p[q], a0);
                a1 = fdot2(wi0[1][q], xc.p[q], a1);
                a2 = fdot2(wi0[2][q], xc.p[q], a2);
            }
            a0 += qxor1(a0); a0 += qxor2(a0);
            a1 += qxor1(a1); a1 += qxor2(a1);
            a2 += qxor1(a2); a2 += qxor2(a2);
            if (lead) {
                sm.gi0[nxt][j] = a0;
                sm.gi0[nxt][j + HH] = a1;
                sm.gi0[nxt][j + 2 * HH] = a2;
            }
        }
        if (tid < 128 && (s & 15) == 8 && s + 8 < TT) {    // commit x chunk
            const int buf = ((s >> 4) + 1) & 1;
            ((h2*)&sm.xh[buf][0][0])[2 * tid]     = cvt2(pf.x, pf.y);
            ((h2*)&sm.xh[buf][0][0])[2 * tid + 1] = cvt2(pf.z, pf.w);
        }
        __syncthreads();                                   // the ONLY per-step barrier
    }
}

// ---------------- waves 8-11: layer 0 + fused fc ----------------
__device__ __forceinline__ void role_L0(
    SM& sm, const float* __restrict__ W_hh0, const float* __restrict__ b_hh0,
    const float* __restrict__ fc_w, const float* __restrict__ fc_b,
    float* __restrict__ hstack_l0)
{
    const int u = threadIdx.x - 512;       // 0..255
    const int j = u >> 1, kq = u & 1;      // 128 j x 2-way K split (lane pairs)
    const int o = u & 31, ks = u >> 5;     // fc: 32 outputs x 8-way K split

    h2 wh0[3][32];
    #pragma unroll
    for (int g = 0; g < 3; ++g) {
        const float* ph = &W_hh0[(size_t)(j + g * HH) * HH + kq * 64];
        #pragma unroll
        for (int m = 0; m < 32; ++m) {
            float2 f = *(const float2*)&ph[2 * m];
            wh0[g][m] = cvt2(f.x, f.y);
        }
    }
    const bool lead = (kq == 0);
    const float bhr = lead ? b_hh0[j] : 0.f;
    const float bhz = lead ? b_hh0[j + HH] : 0.f;
    const float bhn = lead ? b_hh0[j + 2 * HH] : 0.f;
    float fcr[16];                          // register-resident fc row slice
    #pragma unroll
    for (int m = 0; m < 16; ++m) fcr[m] = fc_w[o * HH + ks * 16 + m];
    const float fcbr = (u < NOUT) ? fc_b[u] : 0.f;

    __syncthreads();                        // barrier #1 (match L1)
    __syncthreads();                        // barrier #2 (match L1)

    float hprev = 0.f;
    for (int s = 0; s <= TT + 4; ++s) {
        const int cur = s & 1, nxt = cur ^ 1;
        // hoist gi0 LDS reads: issue early, consumed after the dot block
        float gir = 0.f, giz = 0.f, gin = 0.f;
        if (s <= TT - 1) {
            gir = sm.gi0[cur][j];
            giz = sm.gi0[cur][j + HH];
            gin = sm.gi0[cur][j + 2 * HH];
        }
        if (s <= TT - 1) {                  // h0[s]
            // split accumulators: 16-deep chains instead of 32-deep
            float ahr0 = bhr, ahz0 = bhz, ahn0 = bhn;
            float ahr1 = 0.f, ahz1 = 0.f, ahn1 = 0.f;
            #pragma unroll
            for (int i = 0; i < 4; ++i) {   // STATIC indices only
                H8 hc; hc.v = *(const h8*)&sm.hf0[cur][kq * 64 + i * 8];
                #pragma unroll
                for (int q = 0; q < 4; ++q) {
                    const int m = 4 * i + q;
                    ahr0 = fdot2(wh0[0][m], hc.p[q], ahr0);
                    ahz0 = fdot2(wh0[1][m], hc.p[q], ahz0);
                    ahn0 = fdot2(wh0[2][m], hc.p[q], ahn0);
                }
            }
            #pragma unroll
            for (int i = 4; i < 8; ++i) {
                H8 hc; hc.v = *(const h8*)&sm.hf0[cur][kq * 64 + i * 8];
                #pragma unroll
                for (int q = 0; q < 4; ++q) {
                    const int m = 4 * i + q;
                    ahr1 = fdot2(wh0[0][m], hc.p[q], ahr1);
                    ahz1 = fdot2(wh0[1][m], hc.p[q], ahz1);
                    ahn1 = fdot2(wh0[2][m], hc.p[q], ahn1);
                }
            }
            float ahr = ahr0 + ahr1, ahz = ahz0 + ahz1, ahn = ahn0 + ahn1;
            ahr += qxor1(ahr);
            ahz += qxor1(ahz);
            ahn += qxor1(ahn);
            float rg = fast_sigmoid(gir + ahr);
            float zg = fast_sigmoid(giz + ahz);
            float ng = fast_tanh(gin + rg * ahn);
            float hn = (1.f - zg) * ng + zg * hprev;
            hprev = hn;
            if (kq == 0) sm.hf0[nxt][j] = (_Float16)hn;
            if (s == TT - 1 && kq == 1) hstack_l0[j] = hn;
        }
        if (s >= 2 && s <= TT + 1) {        // fc partial on h1[s-2]
            const float* hv = &sm.hs1[cur][ks * 16];
            float ssum = 0.f;
            #pragma unroll
            for (int m = 0; m < 16; ++m) ssum = fmaf(hv[m], fcr[m], ssum);
            sm.pfc[cur][o * 9 + ks] = ssum;
        }
        if (s >= 3 && s <= TT + 2 && u < NOUT) {  // fc reduce -> LDS out ring
            float ssum = fcbr;
            #pragma unroll
            for (int m = 0; m < 8; ++m) ssum += sm.pfc[nxt][u * 9 + m];
            sm.outbuf[(s - 3) & 31][u] = ssum;
        }
        __syncthreads();                    // the ONLY per-step barrier
    }
}

extern "C" __global__ void __launch_bounds__(768, 3)
gru_fused_kernel(
    const float* __restrict__ x,
    const float* __restrict__ W_ih0, const float* __restrict__ W_hh0,
    const float* __restrict__ b_ih0, const float* __restrict__ b_hh0,
    const float* __restrict__ W_ih1, const float* __restrict__ W_hh1,
    const float* __restrict__ b_ih1, const float* __restrict__ b_hh1,
    const float* __restrict__ fc_w, const float* __restrict__ fc_b,
    float* __restrict__ out, float* __restrict__ hstack)
{
    __shared__ SM sm;
    const int b = blockIdx.x;
    if (threadIdx.x < 512) {
        role_L1(sm, x + (size_t)b * TT * IN0,
                W_ih1, W_hh1, b_ih1, b_hh1, W_ih0, b_ih0,
                out + (size_t)b * TT * NOUT,
                hstack + (size_t)(BB + b) * HH);
    } else {
        role_L0(sm, W_hh0, b_hh0, fc_w, fc_b,
                hstack + (size_t)b * HH);
    }
}

extern "C" void kernel_launch(void* const* d_in, const int* in_sizes, int n_in,
                              void* d_out, int out_size, void* d_ws, size_t ws_size,
                              hipStream_t stream) {
    const float* x     = (const float*)d_in[0];
    const float* W_ih0 = (const float*)d_in[1];
    const float* W_hh0 = (const float*)d_in[2];
    const float* b_ih0 = (const float*)d_in[3];
    const float* b_hh0 = (const float*)d_in[4];
    const float* W_ih1 = (const float*)d_in[5];
    const float* W_hh1 = (const float*)d_in[6];
    const float* b_ih1 = (const float*)d_in[7];
    const float* b_hh1 = (const float*)d_in[8];
    const float* fc_w  = (const float*)d_in[9];
    const float* fc_b  = (const float*)d_in[10];

    float* out    = (float*)d_out;                 // [B,T,32]
    float* hstack = out + (size_t)BB * TT * NOUT;  // [2,B,128]

    gru_fused_kernel<<<BB, 768, 0, stream>>>(
        x, W_ih0, W_hh0, b_ih0, b_hh0,
        W_ih1, W_hh1, b_ih1, b_hh1,
        fc_w, fc_b, out, hstack);
}